// Round 1
// baseline (214565.527 us; speedup 1.0000x reference)
//
#include <hip/hip_runtime.h>

#define SLEN 512
#define BATCH 64
#define IDIM 256
#define HDIM 1024
#define ODIM 128
#define NBLK 256
#define NTHR 256

__device__ __forceinline__ float sigmoidf_(float v) {
  return 1.0f / (1.0f + __expf(-v));
}

// 2-level grid barrier: 8 leaf counters (64B apart) + root at sy[0].
// Cumulative counts (no reset): at sync #idx each leaf reaches 32*idx,
// root reaches 8*idx. Safe: a block can only arrive at idx+1 after root
// passed 8*idx, which requires every block to have arrived at idx.
__device__ __forceinline__ void gsync(unsigned* sy, int blk, unsigned idx) {
  __syncthreads();
  if (threadIdx.x == 0) {
    unsigned* leaf = sy + 16 + 16 * (blk & 7);
    __threadfence();
    unsigned old = __hip_atomic_fetch_add(leaf, 1u, __ATOMIC_ACQ_REL, __HIP_MEMORY_SCOPE_AGENT);
    if (old == 32u * idx - 1u)
      __hip_atomic_fetch_add(sy, 1u, __ATOMIC_ACQ_REL, __HIP_MEMORY_SCOPE_AGENT);
    while (__hip_atomic_load(sy, __ATOMIC_ACQUIRE, __HIP_MEMORY_SCOPE_AGENT) < 8u * idx)
      __builtin_amdgcn_s_sleep(2);
    __threadfence();
  }
  __syncthreads();
}

// Accumulate acc[t] += sum_k src[b][k] * wr[t][c0+k] over klen (multiple of 256),
// staging src (optionally elementwise-multiplied by srcB) through LDS in
// 256-wide chunks. Thread layout: b = tid&63 (batch lane), wave owns NCW cols.
// LDS stride 257 -> (b*257+k)%32 = (b+k)%32 -> 2 lanes/bank (free).
template<bool MUL, int NCW>
__device__ __forceinline__ void dot_phase(float* acc,
    const float* __restrict__ srcA, int ldA,
    const float* __restrict__ srcB,
    int klen,
    const float* const* wr,
    float (*lds)[257])
{
  const int tid = threadIdx.x;
  const int b = tid & 63;
  for (int c0 = 0; c0 < klen; c0 += 256) {
    __syncthreads();
    #pragma unroll
    for (int i = 0; i < 16; ++i) {
      const int fo = (tid + (i << 8)) << 2;   // float offset, 4 floats/thread/iter
      const int row = fo >> 8;                // 0..63
      const int col = fo & 255;
      float4 v = *(const float4*)(srcA + (size_t)row * ldA + c0 + col);
      if constexpr (MUL) {
        float4 u = *(const float4*)(srcB + (size_t)row * ldA + c0 + col);
        v.x *= u.x; v.y *= u.y; v.z *= u.z; v.w *= u.w;
      }
      *(float4*)(&lds[row][col]) = v;
    }
    __syncthreads();
    #pragma unroll 8
    for (int k = 0; k < 256; ++k) {
      const float a = lds[b][k];
      #pragma unroll
      for (int t = 0; t < NCW; ++t)
        acc[t] = fmaf(a, wr[t][c0 + k], acc[t]);
    }
  }
}

__global__ __launch_bounds__(NTHR) void gru_persistent(
    const float* __restrict__ x,
    const float* __restrict__ Wr0, const float* __restrict__ br0,
    const float* __restrict__ Wz0, const float* __restrict__ bz0,
    const float* __restrict__ Wh0, const float* __restrict__ bh0,
    const float* __restrict__ Wr1, const float* __restrict__ br1,
    const float* __restrict__ Wz1, const float* __restrict__ bz1,
    const float* __restrict__ Wh1, const float* __restrict__ bh1,
    const float* __restrict__ Wout, const float* __restrict__ bout,
    float* __restrict__ out, float* __restrict__ ws)
{
  __shared__ float lds[64][257];
  __shared__ float red[NTHR];

  const int blk = blockIdx.x;
  const int tid = threadIdx.x;
  const int b = tid & 63;
  const int wv = tid >> 6;

  unsigned* sy = (unsigned*)ws;
  float* h0A = ws + 256;                 // zeroed by memset each launch
  float* h1A = h0A + BATCH * HDIM;       // zeroed by memset each launch
  float* h0B = h1A + BATCH * HDIM;
  float* h1B = h0B + BATCH * HDIM;
  float* rws = h1B + BATCH * HDIM;       // r0 / r1 (reused across layers)
  float* zws = rws + BATCH * HDIM;       // z0 / z1

  unsigned sidx = 0;

  for (int s = 0; s <= SLEN; ++s) {
    const float* h0c = (s & 1) ? h0B : h0A;
    float*       h0n = (s & 1) ? h0A : h0B;
    const float* h1c = (s & 1) ? h1B : h1A;
    float*       h1n = (s & 1) ? h1A : h1B;

    // ---- stage 1: layer0 r,z gates; blocks<128 -> r, >=128 -> z (8 cols/block)
    if (s < SLEN) {
      const bool isR = (blk < 128);
      const float* W    = isR ? Wr0 : Wz0;
      const float* bias = isR ? br0 : bz0;
      float*       dst  = isR ? rws : zws;
      const int j0 = (isR ? blk : blk - 128) * 8 + wv * 2;
      const float* wrA[2] = { W + (size_t)j0 * 1280, W + (size_t)(j0 + 1) * 1280 };
      float acc[2] = {0.f, 0.f};
      dot_phase<false, 2>(acc, x + (size_t)s * BATCH * IDIM, IDIM, nullptr, IDIM, wrA, lds);
      const float* wrB[2] = { wrA[0] + IDIM, wrA[1] + IDIM };
      dot_phase<false, 2>(acc, h0c, HDIM, nullptr, HDIM, wrB, lds);
      #pragma unroll
      for (int t = 0; t < 2; ++t)
        dst[(size_t)b * HDIM + j0 + t] = sigmoidf_(acc[t] + bias[j0 + t]);
    }
    // ---- merged: out(s-1) on blocks 128..255 (1 out-col each), k split by wave
    if (s > 0 && blk >= 128) {
      const int jo = blk - 128;
      const float* wo = Wout + (size_t)jo * HDIM;
      const int kb = wv * 256;
      float p = 0.f;
      #pragma unroll 8
      for (int k = 0; k < 256; ++k)
        p = fmaf(h1c[(size_t)b * HDIM + kb + k], wo[kb + k], p);
      __syncthreads();
      red[wv * 64 + b] = p;
      __syncthreads();
      if (wv == 0) {
        float t4 = red[b] + red[64 + b] + red[128 + b] + red[192 + b] + bout[jo];
        out[((size_t)(s - 1) * BATCH + b) * ODIM + jo] = t4;
      }
    }
    if (s == SLEN) break;
    gsync(sy, blk, ++sidx);

    // ---- stage 2: h~0 = tanh([x, r0*h0] @ Wh0^T + b), h0_new update (4 cols/block)
    {
      const int j = blk * 4 + wv;
      const float* wrA[1] = { Wh0 + (size_t)j * 1280 };
      float acc[1] = {0.f};
      dot_phase<false, 1>(acc, x + (size_t)s * BATCH * IDIM, IDIM, nullptr, IDIM, wrA, lds);
      const float* wrB[1] = { wrA[0] + IDIM };
      dot_phase<true, 1>(acc, rws, HDIM, h0c, HDIM, wrB, lds);
      const float ht = tanhf(acc[0] + bh0[j]);
      const float z  = zws[(size_t)b * HDIM + j];
      const float hp = h0c[(size_t)b * HDIM + j];
      h0n[(size_t)b * HDIM + j] = fmaf(z, ht - hp, hp);
    }
    gsync(sy, blk, ++sidx);

    // ---- stage 3: layer1 r,z gates over [h0_new, h1]
    {
      const bool isR = (blk < 128);
      const float* W    = isR ? Wr1 : Wz1;
      const float* bias = isR ? br1 : bz1;
      float*       dst  = isR ? rws : zws;   // reuse: layer0 r,z consumed in stage 2
      const int j0 = (isR ? blk : blk - 128) * 8 + wv * 2;
      const float* wrA[2] = { W + (size_t)j0 * 2048, W + (size_t)(j0 + 1) * 2048 };
      float acc[2] = {0.f, 0.f};
      dot_phase<false, 2>(acc, h0n, HDIM, nullptr, HDIM, wrA, lds);
      const float* wrB[2] = { wrA[0] + HDIM, wrA[1] + HDIM };
      dot_phase<false, 2>(acc, h1c, HDIM, nullptr, HDIM, wrB, lds);
      #pragma unroll
      for (int t = 0; t < 2; ++t)
        dst[(size_t)b * HDIM + j0 + t] = sigmoidf_(acc[t] + bias[j0 + t]);
    }
    gsync(sy, blk, ++sidx);

    // ---- stage 4: h~1 = tanh([h0_new, r1*h1] @ Wh1^T + b), h1_new update
    {
      const int j = blk * 4 + wv;
      const float* wrA[1] = { Wh1 + (size_t)j * 2048 };
      float acc[1] = {0.f};
      dot_phase<false, 1>(acc, h0n, HDIM, nullptr, HDIM, wrA, lds);
      const float* wrB[1] = { wrA[0] + HDIM };
      dot_phase<true, 1>(acc, rws, HDIM, h1c, HDIM, wrB, lds);
      const float ht = tanhf(acc[0] + bh1[j]);
      const float z  = zws[(size_t)b * HDIM + j];
      const float hp = h1c[(size_t)b * HDIM + j];
      h1n[(size_t)b * HDIM + j] = fmaf(z, ht - hp, hp);
    }
    gsync(sy, blk, ++sidx);
  }

  // finals: SLEN=512 even -> "current" buffers at s=512 are A
  {
    const size_t base = (size_t)SLEN * BATCH * ODIM;
    const int u = blk * NTHR + tid;          // 0..65535
    out[base + u] = h0A[u];
    out[base + BATCH * HDIM + u] = h1A[u];
  }
}

extern "C" void kernel_launch(void* const* d_in, const int* in_sizes, int n_in,
                              void* d_out, int out_size, void* d_ws, size_t ws_size,
                              hipStream_t stream) {
  const float* xx  = (const float*)d_in[0];
  const float* Wr0 = (const float*)d_in[1];
  const float* br0 = (const float*)d_in[2];
  const float* Wz0 = (const float*)d_in[3];
  const float* bz0 = (const float*)d_in[4];
  const float* Wh0 = (const float*)d_in[5];
  const float* bh0 = (const float*)d_in[6];
  const float* Wr1 = (const float*)d_in[7];
  const float* br1 = (const float*)d_in[8];
  const float* Wz1 = (const float*)d_in[9];
  const float* bz1 = (const float*)d_in[10];
  const float* Wh1 = (const float*)d_in[11];
  const float* bh1 = (const float*)d_in[12];
  const float* Wou = (const float*)d_in[13];
  const float* bou = (const float*)d_in[14];

  // zero: sync counters (1024B) + h0A + h1A (contiguous at ws front)
  hipMemsetAsync(d_ws, 0, 1024 + 2 * BATCH * HDIM * sizeof(float), stream);

  gru_persistent<<<dim3(NBLK), dim3(NTHR), 0, stream>>>(
      xx, Wr0, br0, Wz0, bz0, Wh0, bh0,
      Wr1, br1, Wz1, bz1, Wh1, bh1, Wou, bou,
      (float*)d_out, (float*)d_ws);
}

// Round 2
// 154403.235 us; speedup vs baseline: 1.3896x; 1.3896x over previous
//
#include <hip/hip_runtime.h>

#define SLEN 512
#define BATCH 64
#define IDIM 256
#define HDIM 1024
#define ODIM 128
#define NBLK 256
#define NTHR 512

__device__ __forceinline__ float sigmoidf_(float v) {
  return 1.0f / (1.0f + __expf(-v));
}

// 2-level grid barrier: 8 leaf counters + root at sy[0]. Cumulative counts.
__device__ __forceinline__ void gsync(unsigned* sy, int blk, unsigned idx) {
  __syncthreads();
  if (threadIdx.x == 0) {
    unsigned* leaf = sy + 16 + 16 * (blk & 7);
    __threadfence();
    unsigned old = __hip_atomic_fetch_add(leaf, 1u, __ATOMIC_ACQ_REL, __HIP_MEMORY_SCOPE_AGENT);
    if (old == 32u * idx - 1u)
      __hip_atomic_fetch_add(sy, 1u, __ATOMIC_ACQ_REL, __HIP_MEMORY_SCOPE_AGENT);
    while (__hip_atomic_load(sy, __ATOMIC_ACQUIRE, __HIP_MEMORY_SCOPE_AGENT) < 8u * idx)
      __builtin_amdgcn_s_sleep(2);
    __threadfence();
  }
  __syncthreads();
}

// Linear W copy global->LDS (rows for a block's 8 cols are contiguous).
__device__ __forceinline__ void stage_w(const float* __restrict__ src, float* dst, int nfloat) {
  for (int i = threadIdx.x * 4; i < nfloat; i += NTHR * 4) {
    float4 v = *(const float4*)(src + i);
    *(float4*)(dst + i) = v;
  }
}

// acc[c] += sum over NCH chunks of 32 k: A[rr][32j + kg4 .. +3] (global, coalesced)
// dot W rows in LDS. wl points at (wl_base + kbase + kg4); KW = full W row stride.
template<int NCH, int KW>
__device__ __forceinline__ void seg_dot8(float* acc,
    const float* __restrict__ A, int ldA, int rr, int kg4,
    const float* wl)
{
  const float* ap = A + (size_t)rr * ldA + kg4;
  #pragma unroll 8
  for (int j = 0; j < NCH; ++j) {
    float4 a = *(const float4*)(ap + 32 * j);
    #pragma unroll
    for (int c = 0; c < 8; ++c) {
      const float4 w = *(const float4*)(wl + c * KW + 32 * j);
      acc[c] = fmaf(a.x, w.x, acc[c]);
      acc[c] = fmaf(a.y, w.y, acc[c]);
      acc[c] = fmaf(a.z, w.z, acc[c]);
      acc[c] = fmaf(a.w, w.w, acc[c]);
    }
  }
}

__device__ __forceinline__ float fold8(float v) {
  v += __shfl_xor(v, 8);
  v += __shfl_xor(v, 16);
  v += __shfl_xor(v, 32);
  return v;
}

__global__ __launch_bounds__(NTHR) void gru_pers(
    const float* __restrict__ x,
    const float* __restrict__ Wr0, const float* __restrict__ br0,
    const float* __restrict__ Wz0, const float* __restrict__ bz0,
    const float* __restrict__ Wh0, const float* __restrict__ bh0,
    const float* __restrict__ Wr1, const float* __restrict__ br1,
    const float* __restrict__ Wz1, const float* __restrict__ bz1,
    const float* __restrict__ Wh1, const float* __restrict__ bh1,
    const float* __restrict__ Wout, const float* __restrict__ bout,
    float* __restrict__ out, float* __restrict__ ws)
{
  __shared__ float wl[8 * 2048];   // 64 KB

  const int blk = blockIdx.x;
  const int tid = threadIdx.x;
  const int l = tid & 63;
  const int rr = ((tid >> 6) << 3) + (l & 7);   // row 0..63
  const int kg4 = (l >> 3) << 2;                // k-offset floats: 0,4,...,28
  const bool str = (l & 56) == 0;               // kg==0 lanes store

  unsigned* sy = (unsigned*)ws;
  float* h0A = ws + 256;
  float* h1A = h0A + BATCH * HDIM;
  float* h0B = h1A + BATCH * HDIM;
  float* h1B = h0B + BATCH * HDIM;
  float* rh  = h1B + BATCH * HDIM;   // r0*h0c, then r1*h1c
  float* zz  = rh  + BATCH * HDIM;   // z0, then z1

  unsigned sidx = 0;

  for (int s = 0; s < SLEN; ++s) {
    const float* h0c = (s & 1) ? h0B : h0A;
    float*       h0n = (s & 1) ? h0A : h0B;
    const float* h1c = (s & 1) ? h1B : h1A;
    float*       h1n = (s & 1) ? h1A : h1B;
    const float* xs = x + (size_t)s * BATCH * IDIM;

    // ---------- stage 1: r0 (blk<128) / z0 (blk>=128), 8 cols each ----------
    {
      const bool isR = (blk < 128);
      const int j0 = (blk & 127) * 8;
      stage_w((isR ? Wr0 : Wz0) + (size_t)j0 * 1280, wl, 8 * 1280);
      __syncthreads();
      float acc[8] = {0.f,0.f,0.f,0.f,0.f,0.f,0.f,0.f};
      seg_dot8<8, 1280>(acc, xs, IDIM, rr, kg4, wl + kg4);
      seg_dot8<32, 1280>(acc, h0c, HDIM, rr, kg4, wl + 256 + kg4);
      #pragma unroll
      for (int c = 0; c < 8; ++c) acc[c] = fold8(acc[c]);
      if (str) {
        const float* bias = isR ? br0 : bz0;
        #pragma unroll
        for (int c = 0; c < 8; ++c) {
          float g = sigmoidf_(acc[c] + bias[j0 + c]);
          if (isR) rh[(size_t)rr * HDIM + j0 + c] = g * h0c[(size_t)rr * HDIM + j0 + c];
          else     zz[(size_t)rr * HDIM + j0 + c] = g;
        }
      }
    }
    gsync(sy, blk, ++sidx);

    // ---------- stage 2: h~0 + h0 update (blk<128) | out(s-1) (blk>=128) ----------
    if (blk < 128) {
      const int j0 = blk * 8;
      stage_w(Wh0 + (size_t)j0 * 1280, wl, 8 * 1280);
      __syncthreads();
      float acc[8] = {0.f,0.f,0.f,0.f,0.f,0.f,0.f,0.f};
      seg_dot8<8, 1280>(acc, xs, IDIM, rr, kg4, wl + kg4);
      seg_dot8<32, 1280>(acc, rh, HDIM, rr, kg4, wl + 256 + kg4);
      #pragma unroll
      for (int c = 0; c < 8; ++c) acc[c] = fold8(acc[c]);
      if (str) {
        #pragma unroll
        for (int c = 0; c < 8; ++c) {
          float ht = tanhf(acc[c] + bh0[j0 + c]);
          float zv = zz[(size_t)rr * HDIM + j0 + c];
          float hp = h0c[(size_t)rr * HDIM + j0 + c];
          h0n[(size_t)rr * HDIM + j0 + c] = fmaf(zv, ht - hp, hp);
        }
      }
    } else {
      const int jo = blk - 128;
      stage_w(Wout + (size_t)jo * HDIM, wl, HDIM);
      __syncthreads();
      if (s > 0) {
        float a0 = 0.f, a1 = 0.f, a2 = 0.f, a3 = 0.f;
        const float* ap = h1c + (size_t)rr * HDIM + kg4;
        const float* wp = wl + kg4;
        #pragma unroll 8
        for (int j = 0; j < 32; ++j) {
          float4 a = *(const float4*)(ap + 32 * j);
          float4 w = *(const float4*)(wp + 32 * j);
          a0 = fmaf(a.x, w.x, a0);
          a1 = fmaf(a.y, w.y, a1);
          a2 = fmaf(a.z, w.z, a2);
          a3 = fmaf(a.w, w.w, a3);
        }
        float v = fold8((a0 + a1) + (a2 + a3));
        if (str) out[((size_t)(s - 1) * BATCH + rr) * ODIM + jo] = v + bout[jo];
      }
    }
    gsync(sy, blk, ++sidx);

    // ---------- stage 3: r1 (blk<128) / z1 (blk>=128) over [h0n, h1c] ----------
    {
      const bool isR = (blk < 128);
      const int j0 = (blk & 127) * 8;
      stage_w((isR ? Wr1 : Wz1) + (size_t)j0 * 2048, wl, 8 * 2048);
      __syncthreads();
      float acc[8] = {0.f,0.f,0.f,0.f,0.f,0.f,0.f,0.f};
      seg_dot8<32, 2048>(acc, h0n, HDIM, rr, kg4, wl + kg4);
      seg_dot8<32, 2048>(acc, h1c, HDIM, rr, kg4, wl + 1024 + kg4);
      #pragma unroll
      for (int c = 0; c < 8; ++c) acc[c] = fold8(acc[c]);
      if (str) {
        const float* bias = isR ? br1 : bz1;
        #pragma unroll
        for (int c = 0; c < 8; ++c) {
          float g = sigmoidf_(acc[c] + bias[j0 + c]);
          if (isR) rh[(size_t)rr * HDIM + j0 + c] = g * h1c[(size_t)rr * HDIM + j0 + c];
          else     zz[(size_t)rr * HDIM + j0 + c] = g;
        }
      }
    }
    gsync(sy, blk, ++sidx);

    // ---------- stage 4: h~1 + h1 update (blk<128) ----------
    if (blk < 128) {
      const int j0 = blk * 8;
      stage_w(Wh1 + (size_t)j0 * 2048, wl, 8 * 2048);
      __syncthreads();
      float acc[8] = {0.f,0.f,0.f,0.f,0.f,0.f,0.f,0.f};
      seg_dot8<32, 2048>(acc, h0n, HDIM, rr, kg4, wl + kg4);
      seg_dot8<32, 2048>(acc, rh, HDIM, rr, kg4, wl + 1024 + kg4);
      #pragma unroll
      for (int c = 0; c < 8; ++c) acc[c] = fold8(acc[c]);
      if (str) {
        #pragma unroll
        for (int c = 0; c < 8; ++c) {
          float ht = tanhf(acc[c] + bh1[j0 + c]);
          float zv = zz[(size_t)rr * HDIM + j0 + c];
          float hp = h1c[(size_t)rr * HDIM + j0 + c];
          h1n[(size_t)rr * HDIM + j0 + c] = fmaf(zv, ht - hp, hp);
        }
      }
    }
    gsync(sy, blk, ++sidx);
  }

  // ---------- epilogue: out(SLEN-1) on blocks>=128; final states copy ----------
  if (blk >= 128) {
    const int jo = blk - 128;
    stage_w(Wout + (size_t)jo * HDIM, wl, HDIM);
    __syncthreads();
    const float* h1f = h1A;   // SLEN even -> finals in A buffers
    float a0 = 0.f, a1 = 0.f, a2 = 0.f, a3 = 0.f;
    const float* ap = h1f + (size_t)rr * HDIM + kg4;
    const float* wp = wl + kg4;
    #pragma unroll 8
    for (int j = 0; j < 32; ++j) {
      float4 a = *(const float4*)(ap + 32 * j);
      float4 w = *(const float4*)(wp + 32 * j);
      a0 = fmaf(a.x, w.x, a0);
      a1 = fmaf(a.y, w.y, a1);
      a2 = fmaf(a.z, w.z, a2);
      a3 = fmaf(a.w, w.w, a3);
    }
    float v = fold8((a0 + a1) + (a2 + a3));
    if (str) out[((size_t)(SLEN - 1) * BATCH + rr) * ODIM + jo] = v + bout[jo];
  }
  {
    const size_t base = (size_t)SLEN * BATCH * ODIM;
    const int u = blk * NTHR + tid;              // 0..131071, exactly one each
    out[base + u] = h0A[u];                      // h0A/h1A contiguous in ws
  }
}

extern "C" void kernel_launch(void* const* d_in, const int* in_sizes, int n_in,
                              void* d_out, int out_size, void* d_ws, size_t ws_size,
                              hipStream_t stream) {
  const float* xx  = (const float*)d_in[0];
  const float* Wr0 = (const float*)d_in[1];
  const float* br0 = (const float*)d_in[2];
  const float* Wz0 = (const float*)d_in[3];
  const float* bz0 = (const float*)d_in[4];
  const float* Wh0 = (const float*)d_in[5];
  const float* bh0 = (const float*)d_in[6];
  const float* Wr1 = (const float*)d_in[7];
  const float* br1 = (const float*)d_in[8];
  const float* Wz1 = (const float*)d_in[9];
  const float* bz1 = (const float*)d_in[10];
  const float* Wh1 = (const float*)d_in[11];
  const float* bh1 = (const float*)d_in[12];
  const float* Wou = (const float*)d_in[13];
  const float* bou = (const float*)d_in[14];

  // zero: sync counters (1024B) + h0A + h1A (contiguous at ws front)
  hipMemsetAsync(d_ws, 0, 1024 + 2 * BATCH * HDIM * sizeof(float), stream);

  gru_pers<<<dim3(NBLK), dim3(NTHR), 0, stream>>>(
      xx, Wr0, br0, Wz0, bz0, Wh0, bh0,
      Wr1, br1, Wz1, bz1, Wh1, bh1, Wou, bou,
      (float*)d_out, (float*)d_ws);
}

// Round 3
// 77905.621 us; speedup vs baseline: 2.7542x; 1.9819x over previous
//
#include <hip/hip_runtime.h>

#define SLEN 512
#define BATCH 64
#define IDIM 256
#define HDIM 1024
#define ODIM 128
#define NBLK 256
#define NTHR 512

typedef unsigned short ushortT;
typedef __attribute__((ext_vector_type(8))) short short8;
typedef __attribute__((ext_vector_type(4))) float f32x4;

__device__ __forceinline__ ushortT f2bf(float f) {
  unsigned u = __float_as_uint(f);
  unsigned r = (u + 0x7FFFu + ((u >> 16) & 1u)) >> 16;
  return (ushortT)r;
}
__device__ __forceinline__ float bf2f(ushortT u) {
  return __uint_as_float(((unsigned)u) << 16);
}

// pack A/B fragment halves: src[0..3] -> e0..3 (k=+0..3), src[16..19] -> e4..7 (k=+16..19)
__device__ __forceinline__ void pack2(const float* __restrict__ s, ushortT* d) {
  float4 a = *(const float4*)s;
  float4 b = *(const float4*)(s + 16);
  short8 v;
  v[0]=(short)f2bf(a.x); v[1]=(short)f2bf(a.y); v[2]=(short)f2bf(a.z); v[3]=(short)f2bf(a.w);
  v[4]=(short)f2bf(b.x); v[5]=(short)f2bf(b.y); v[6]=(short)f2bf(b.z); v[7]=(short)f2bf(b.w);
  *(short8*)d = v;
}

// store one f32 value into a fragment-ordered bf16 mirror at (row, cL)
__device__ __forceinline__ void mir_store(ushortT* M, int row, int cL, float v) {
  int kt = cL >> 5, c5 = cL & 31;
  int h = c5 >> 4, g = (c5 >> 2) & 3, j = c5 & 3;
  int u = ((kt * 4 + (row >> 4)) * 64) + 16 * g + (row & 15);
  M[(size_t)u * 8 + h * 4 + j] = f2bf(v);
}

// 2-level grid barrier (proven in R1/R2): 8 leaves + root, cumulative counts.
__device__ __forceinline__ void gsync(unsigned* sy, int blk, unsigned idx) {
  __syncthreads();
  if (threadIdx.x == 0) {
    unsigned* leaf = sy + 16 + 16 * (blk & 7);
    __threadfence();
    unsigned old = __hip_atomic_fetch_add(leaf, 1u, __ATOMIC_ACQ_REL, __HIP_MEMORY_SCOPE_AGENT);
    if (old == 32u * idx - 1u)
      __hip_atomic_fetch_add(sy, 1u, __ATOMIC_ACQ_REL, __HIP_MEMORY_SCOPE_AGENT);
    while (__hip_atomic_load(sy, __ATOMIC_ACQUIRE, __HIP_MEMORY_SCOPE_AGENT) < 8u * idx)
      __builtin_amdgcn_s_sleep(2);
    __threadfence();
  }
  __syncthreads();
}

__device__ __forceinline__ float fold8(float v) {
  v += __shfl_xor(v, 8);
  v += __shfl_xor(v, 16);
  v += __shfl_xor(v, 32);
  return v;
}

// MFMA stage: A = [mA (SPLIT kts) | mB (NKT-SPLIT kts)], B = block's NC weight cols in WL.
// 8 waves = 4 M-tiles x 2 K-halves; returns reduced acc on waves w<4.
template<int NKT, int SPLIT, int NC>
__device__ __forceinline__ f32x4 stage_mm(
    const ushortT* __restrict__ mA, const ushortT* __restrict__ mB,
    const ushortT* WL, float (*red)[64][4], int l, int w)
{
  const int mt = w & 3, kh = w >> 2;
  const int col = l & 15, g = l >> 4;
  const int lo = kh * (NKT / 2), hi = lo + NKT / 2;
  f32x4 acc = {0.f, 0.f, 0.f, 0.f};
  #pragma unroll 4
  for (int kt = lo; kt < hi; ++kt) {
    const ushortT* s = (kt < SPLIT)
        ? (mA + (size_t)((kt * 4 + mt) * 64 + l) * 8)
        : (mB + (size_t)(((kt - SPLIT) * 4 + mt) * 64 + l) * 8);
    short8 a = *(const short8*)s;
    short8 b = {0,0,0,0,0,0,0,0};
    if (col < NC)
      b = *(const short8*)(&WL[(size_t)(((kt << 2) + g) * NC + col) * 8]);
    acc = __builtin_amdgcn_mfma_f32_16x16x32_bf16(a, b, acc, 0, 0, 0);
  }
  if (w >= 4) *(f32x4*)&red[w - 4][l][0] = acc;
  __syncthreads();
  if (w < 4) { f32x4 o = *(f32x4*)&red[w][l][0]; acc += o; }
  return acc;
}

// x[sN] -> fragment-ordered bf16 mirror slice (8 units per block, threads 0..7)
__device__ __forceinline__ void xform(const float* __restrict__ x, ushortT* MxP,
                                      int sN, int blk, int tid) {
  if (tid >= 8) return;
  int u = (blk << 3) + tid;                 // 0..2047
  int kt = u >> 8, mtu = (u >> 6) & 3, lane = u & 63;
  int row = (mtu << 4) + (lane & 15), gg = lane >> 4;
  const float* p = x + ((size_t)sN * BATCH + row) * IDIM + (kt << 5) + (gg << 2);
  pack2(p, MxP + (size_t)u * 8);
}

__device__ __forceinline__ void out_dot(const float* __restrict__ h1f,
                                        const ushortT* WLo,
                                        const float* __restrict__ bout,
                                        float* __restrict__ out,
                                        int s_store, int jo, int tid) {
  const int l = tid & 63, w = tid >> 6;
  const int rr = (w << 3) + (l & 7);
  const int k0base = (l >> 3) << 3;         // 0,8,...,56
  float a0 = 0.f, a1 = 0.f;
  #pragma unroll 4
  for (int j = 0; j < 16; ++j) {
    int k0 = k0base + (j << 6);
    float4 hA = *(const float4*)(h1f + (size_t)rr * HDIM + k0);
    float4 hB = *(const float4*)(h1f + (size_t)rr * HDIM + k0 + 4);
    union { short8 v; ushortT u[8]; } W;
    W.v = *(const short8*)(&WLo[k0]);
    a0 = fmaf(hA.x, bf2f(W.u[0]), a0);
    a0 = fmaf(hA.y, bf2f(W.u[1]), a0);
    a0 = fmaf(hA.z, bf2f(W.u[2]), a0);
    a0 = fmaf(hA.w, bf2f(W.u[3]), a0);
    a1 = fmaf(hB.x, bf2f(W.u[4]), a1);
    a1 = fmaf(hB.y, bf2f(W.u[5]), a1);
    a1 = fmaf(hB.z, bf2f(W.u[6]), a1);
    a1 = fmaf(hB.w, bf2f(W.u[7]), a1);
  }
  float v = fold8(a0 + a1);
  if ((l & 56) == 0)
    out[((size_t)s_store * BATCH + rr) * ODIM + jo] = v + bout[jo];
}

__global__ __launch_bounds__(NTHR) void gru_mfma(
    const float* __restrict__ x,
    const float* __restrict__ Wr0, const float* __restrict__ br0,
    const float* __restrict__ Wz0, const float* __restrict__ bz0,
    const float* __restrict__ Wh0, const float* __restrict__ bh0,
    const float* __restrict__ Wr1, const float* __restrict__ br1,
    const float* __restrict__ Wz1, const float* __restrict__ bz1,
    const float* __restrict__ Wh1, const float* __restrict__ bh1,
    const float* __restrict__ Wout, const float* __restrict__ bout,
    float* __restrict__ out, char* __restrict__ ws)
{
  __shared__ ushortT WL1[40 * 4 * 8 * 8];   // r0|z0, K=1280, 8 cols
  __shared__ ushortT WL2[40 * 4 * 4 * 8];   // h0,   K=1280, 4 cols
  __shared__ ushortT WL3[64 * 4 * 8 * 8];   // r1|z1, K=2048, 8 cols
  __shared__ ushortT WL4[64 * 4 * 4 * 8];   // h1,   K=2048, 4 cols
  __shared__ ushortT WLo[1024];             // out col (blk>=128)
  __shared__ float red[4][64][4];

  const int blk = blockIdx.x;
  const int tid = threadIdx.x;
  const int l = tid & 63;
  const int w = tid >> 6;
  const int col = l & 15, g = l >> 4;

  unsigned* sy = (unsigned*)ws;
  float* h0f   = (float*)(ws + 1024);
  float* h1f   = (float*)(ws + 263168);
  ushortT* Mh0  = (ushortT*)(ws + 525312);
  ushortT* Mh1  = (ushortT*)(ws + 656384);
  float* zf    = (float*)(ws + 787456);
  ushortT* Mrh0 = (ushortT*)(ws + 1049600);
  ushortT* Mrh1 = (ushortT*)(ws + 1180672);
  ushortT* Mx   = (ushortT*)(ws + 1311744);  // 2 x 16384 ushorts

  // ---- one-time: weights -> LDS (bf16, fragment order) ----
  for (int u = tid; u < 40 * 4 * 8; u += NTHR) {
    int kt = u >> 5, gg = (u >> 3) & 3, c = u & 7;
    const float* src = (c < 4 ? Wr0 + (size_t)((blk << 2) + c) * 1280
                              : Wz0 + (size_t)((blk << 2) + c - 4) * 1280)
                       + (kt << 5) + (gg << 2);
    pack2(src, &WL1[(size_t)u * 8]);
  }
  for (int u = tid; u < 40 * 4 * 4; u += NTHR) {
    int kt = u >> 4, gg = (u >> 2) & 3, c = u & 3;
    const float* src = Wh0 + (size_t)((blk << 2) + c) * 1280 + (kt << 5) + (gg << 2);
    pack2(src, &WL2[(size_t)u * 8]);
  }
  for (int u = tid; u < 64 * 4 * 8; u += NTHR) {
    int kt = u >> 5, gg = (u >> 3) & 3, c = u & 7;
    const float* src = (c < 4 ? Wr1 + (size_t)((blk << 2) + c) * 2048
                              : Wz1 + (size_t)((blk << 2) + c - 4) * 2048)
                       + (kt << 5) + (gg << 2);
    pack2(src, &WL3[(size_t)u * 8]);
  }
  for (int u = tid; u < 64 * 4 * 4; u += NTHR) {
    int kt = u >> 4, gg = (u >> 2) & 3, c = u & 3;
    const float* src = Wh1 + (size_t)((blk << 2) + c) * 2048 + (kt << 5) + (gg << 2);
    pack2(src, &WL4[(size_t)u * 8]);
  }
  if (blk >= 128) {
    for (int u = tid; u < 256; u += NTHR) {
      float4 a = *(const float4*)(Wout + (size_t)(blk - 128) * HDIM + (u << 2));
      WLo[(u << 2) + 0] = f2bf(a.x);
      WLo[(u << 2) + 1] = f2bf(a.y);
      WLo[(u << 2) + 2] = f2bf(a.z);
      WLo[(u << 2) + 3] = f2bf(a.w);
    }
  }
  xform(x, Mx, 0, blk, tid);   // x_0 mirror, parity 0

  unsigned sidx = 0;
  gsync(sy, blk, ++sidx);

  for (int s = 0; s < SLEN; ++s) {
    const ushortT* MxP = Mx + (size_t)(s & 1) * 16384;

    // ---- S1: r0|z0 over [x_s | h0]; out(s-1) on blk>=128 ----
    {
      f32x4 acc = stage_mm<40, 8, 8>(MxP, Mh0, WL1, red, l, w);
      if (w < 4 && col < 8) {
        const bool isr = col < 4;
        const int colg = (blk << 2) + (col & 3);
        const float bias = isr ? br0[colg] : bz0[colg];
        #pragma unroll
        for (int r = 0; r < 4; ++r) {
          int row = (w << 4) + (g << 2) + r;
          float sg = 1.f / (1.f + __expf(-(acc[r] + bias)));
          if (isr) mir_store(Mrh0, row, colg, sg * h0f[(size_t)row * HDIM + colg]);
          else     zf[(size_t)row * HDIM + colg] = sg;
        }
      }
      if (s > 0 && blk >= 128)
        out_dot(h1f, WLo, bout, out, s - 1, blk - 128, tid);
    }
    gsync(sy, blk, ++sidx);

    // ---- S2: h~0 over [x_s | r0*h0]; update h0 ----
    {
      f32x4 acc = stage_mm<40, 8, 4>(MxP, Mrh0, WL2, red, l, w);
      if (w < 4 && col < 4) {
        const int colg = (blk << 2) + col;
        const float bias = bh0[colg];
        #pragma unroll
        for (int r = 0; r < 4; ++r) {
          int row = (w << 4) + (g << 2) + r;
          float ht = tanhf(acc[r] + bias);
          float zv = zf[(size_t)row * HDIM + colg];
          float hp = h0f[(size_t)row * HDIM + colg];
          float hn = fmaf(zv, ht - hp, hp);
          h0f[(size_t)row * HDIM + colg] = hn;
          mir_store(Mh0, row, colg, hn);
        }
      }
    }
    gsync(sy, blk, ++sidx);

    // ---- S3: r1|z1 over [h0n | h1]; also produce x_{s+1} mirror ----
    {
      if (s + 1 < SLEN)
        xform(x, Mx + (size_t)((s + 1) & 1) * 16384, s + 1, blk, tid);
      f32x4 acc = stage_mm<64, 32, 8>(Mh0, Mh1, WL3, red, l, w);
      if (w < 4 && col < 8) {
        const bool isr = col < 4;
        const int colg = (blk << 2) + (col & 3);
        const float bias = isr ? br1[colg] : bz1[colg];
        #pragma unroll
        for (int r = 0; r < 4; ++r) {
          int row = (w << 4) + (g << 2) + r;
          float sg = 1.f / (1.f + __expf(-(acc[r] + bias)));
          if (isr) mir_store(Mrh1, row, colg, sg * h1f[(size_t)row * HDIM + colg]);
          else     zf[(size_t)row * HDIM + colg] = sg;
        }
      }
    }
    gsync(sy, blk, ++sidx);

    // ---- S4: h~1 over [h0n | r1*h1]; update h1 ----
    {
      f32x4 acc = stage_mm<64, 32, 4>(Mh0, Mrh1, WL4, red, l, w);
      if (w < 4 && col < 4) {
        const int colg = (blk << 2) + col;
        const float bias = bh1[colg];
        #pragma unroll
        for (int r = 0; r < 4; ++r) {
          int row = (w << 4) + (g << 2) + r;
          float ht = tanhf(acc[r] + bias);
          float zv = zf[(size_t)row * HDIM + colg];
          float hp = h1f[(size_t)row * HDIM + colg];
          float hn = fmaf(zv, ht - hp, hp);
          h1f[(size_t)row * HDIM + colg] = hn;
          mir_store(Mh1, row, colg, hn);
        }
      }
    }
    gsync(sy, blk, ++sidx);
  }

  // ---- epilogue: out(SLEN-1) + final states ----
  if (blk >= 128)
    out_dot(h1f, WLo, bout, out, SLEN - 1, blk - 128, tid);
  {
    const size_t base = (size_t)SLEN * BATCH * ODIM;
    const int u = blk * NTHR + tid;          // 0..131071; h0f,h1f contiguous
    out[base + u] = h0f[u];
  }
}

extern "C" void kernel_launch(void* const* d_in, const int* in_sizes, int n_in,
                              void* d_out, int out_size, void* d_ws, size_t ws_size,
                              hipStream_t stream) {
  const float* xx  = (const float*)d_in[0];
  const float* Wr0 = (const float*)d_in[1];
  const float* br0 = (const float*)d_in[2];
  const float* Wz0 = (const float*)d_in[3];
  const float* bz0 = (const float*)d_in[4];
  const float* Wh0 = (const float*)d_in[5];
  const float* bh0 = (const float*)d_in[6];
  const float* Wr1 = (const float*)d_in[7];
  const float* br1 = (const float*)d_in[8];
  const float* Wz1 = (const float*)d_in[9];
  const float* bz1 = (const float*)d_in[10];
  const float* Wh1 = (const float*)d_in[11];
  const float* bh1 = (const float*)d_in[12];
  const float* Wou = (const float*)d_in[13];
  const float* bou = (const float*)d_in[14];

  // zero: sy + h0f + h1f + Mh0 + Mh1 (contiguous prefix of ws)
  hipMemsetAsync(d_ws, 0, 787456, stream);

  gru_mfma<<<dim3(NBLK), dim3(NTHR), 0, stream>>>(
      xx, Wr0, br0, Wz0, bz0, Wh0, bh0,
      Wr1, br1, Wz1, bz1, Wh1, bh1, Wou, bou,
      (float*)d_out, (char*)d_ws);
}

// Round 4
// 22958.813 us; speedup vs baseline: 9.3457x; 3.3933x over previous
//
#include <hip/hip_runtime.h>

#define SLEN 512
#define BATCH 64
#define IDIM 256
#define HDIM 1024
#define ODIM 128
#define NBLK 256
#define NTHR 512

typedef unsigned short ushortT;
typedef __attribute__((ext_vector_type(8))) short short8;
typedef __attribute__((ext_vector_type(4))) float f32x4;

__device__ __forceinline__ ushortT f2bf(float f) {
  unsigned u = __float_as_uint(f);
  unsigned r = (u + 0x7FFFu + ((u >> 16) & 1u)) >> 16;
  return (ushortT)r;
}

// pack A/B fragment halves: src[0..3] -> e0..3, src[16..19] -> e4..7
__device__ __forceinline__ void pack2(const float* __restrict__ s, ushortT* d) {
  float4 a = *(const float4*)s;
  float4 b = *(const float4*)(s + 16);
  short8 v;
  v[0]=(short)f2bf(a.x); v[1]=(short)f2bf(a.y); v[2]=(short)f2bf(a.z); v[3]=(short)f2bf(a.w);
  v[4]=(short)f2bf(b.x); v[5]=(short)f2bf(b.y); v[6]=(short)f2bf(b.z); v[7]=(short)f2bf(b.w);
  *(short8*)d = v;
}

// store one f32 into fragment-ordered bf16 mirror at (row, column cL)
__device__ __forceinline__ void mir_store(ushortT* M, int row, int cL, float v) {
  int kt = cL >> 5, c5 = cL & 31;
  int h = c5 >> 4, g = (c5 >> 2) & 3, j = c5 & 3;
  int u = ((kt * 4 + (row >> 4)) * 64) + 16 * g + (row & 15);
  M[(size_t)u * 8 + h * 4 + j] = f2bf(v);
}

// Grid barrier: leaf adds (32/leaf) -> root (8 adds) -> completer broadcasts to
// 32 padded epoch flags; 8 blocks poll each flag with RELAXED loads + one acquire.
__device__ __forceinline__ void gsync(unsigned* sy, int blk, unsigned idx) {
  __syncthreads();
  if (threadIdx.x == 0) {
    unsigned* leaf = sy + 16 + 16 * (blk & 7);
    unsigned* flags = sy + 256;                    // 32 flags, 16 uints apart
    __threadfence();
    unsigned old = __hip_atomic_fetch_add(leaf, 1u, __ATOMIC_ACQ_REL, __HIP_MEMORY_SCOPE_AGENT);
    if (old == 32u * idx - 1u) {
      unsigned rold = __hip_atomic_fetch_add(sy, 1u, __ATOMIC_ACQ_REL, __HIP_MEMORY_SCOPE_AGENT);
      if (rold == 8u * idx - 1u) {
        #pragma unroll
        for (int f = 0; f < 32; ++f)
          __hip_atomic_store(&flags[16 * f], idx, __ATOMIC_RELAXED, __HIP_MEMORY_SCOPE_AGENT);
      }
    }
    unsigned* myflag = &flags[16 * (blk >> 3)];
    while (__hip_atomic_load(myflag, __ATOMIC_RELAXED, __HIP_MEMORY_SCOPE_AGENT) < idx)
      __builtin_amdgcn_s_sleep(1);
    __hip_atomic_load(myflag, __ATOMIC_ACQUIRE, __HIP_MEMORY_SCOPE_AGENT);
  }
  __syncthreads();
}

__device__ __forceinline__ float fold8(float v) {
  v += __shfl_xor(v, 8);
  v += __shfl_xor(v, 16);
  v += __shfl_xor(v, 32);
  return v;
}

__device__ __forceinline__ short8 lda_(const ushortT* __restrict__ mA,
                                       const ushortT* __restrict__ mB,
                                       int kt, int split, int mt, int l) {
  const ushortT* p = (kt < split)
      ? mA + (size_t)((kt * 4 + mt) * 64 + l) * 8
      : mB + (size_t)(((kt - split) * 4 + mt) * 64 + l) * 8;
  return *(const short8*)p;
}

// N=16 MFMA stage, A = [mA (SPLIT kts) | mB], B = 16 weight cols in WL (LDS).
// 8 waves = 4 M-tiles x 2 K-halves; loads hoisted in chunks of <=16.
template<int NKT, int SPLIT>
__device__ __forceinline__ f32x4 stage_mm16(
    const ushortT* __restrict__ mA, const ushortT* __restrict__ mB,
    const ushortT* WL, float (*red)[64][4], int l, int w)
{
  const int mt = w & 3, kh = w >> 2;
  constexpr int H = NKT / 2;
  constexpr int C1 = (H > 16) ? 16 : H;
  const int lo = kh * H;
  const int g = l >> 4, col = l & 15;
  f32x4 acc = {0.f, 0.f, 0.f, 0.f};
  short8 af[C1];
  #pragma unroll
  for (int t = 0; t < C1; ++t) af[t] = lda_(mA, mB, lo + t, SPLIT, mt, l);
  #pragma unroll
  for (int t = 0; t < C1; ++t) {
    short8 b = *(const short8*)(&WL[(size_t)(((lo + t) * 4 + g) * 16 + col) * 8]);
    acc = __builtin_amdgcn_mfma_f32_16x16x32_bf16(af[t], b, acc, 0, 0, 0);
  }
  if constexpr (H > C1) {
    #pragma unroll
    for (int t = C1; t < H; ++t) af[t - C1] = lda_(mA, mB, lo + t, SPLIT, mt, l);
    #pragma unroll
    for (int t = C1; t < H; ++t) {
      short8 b = *(const short8*)(&WL[(size_t)(((lo + t) * 4 + g) * 16 + col) * 8]);
      acc = __builtin_amdgcn_mfma_f32_16x16x32_bf16(af[t - C1], b, acc, 0, 0, 0);
    }
  }
  if (w >= 4) *(f32x4*)&red[w - 4][l][0] = acc;
  __syncthreads();
  if (w < 4) { f32x4 o = *(f32x4*)&red[w][l][0]; acc += o; }
  return acc;
}

__device__ __forceinline__ void out_dot(const float* __restrict__ h1f,
                                        const ushortT* WLo, float bo,
                                        float* __restrict__ out,
                                        int s_store, int jo, int tid) {
  const int l = tid & 63, w = tid >> 6;
  const int rr = (w << 3) + (l & 7);
  const int k0base = (l >> 3) << 3;
  float a0 = 0.f, a1 = 0.f;
  #pragma unroll 4
  for (int j = 0; j < 16; ++j) {
    int k0 = k0base + (j << 6);
    float4 hA = *(const float4*)(h1f + (size_t)rr * HDIM + k0);
    float4 hB = *(const float4*)(h1f + (size_t)rr * HDIM + k0 + 4);
    union { short8 v; ushortT u[8]; } W;
    W.v = *(const short8*)(&WLo[k0]);
    a0 = fmaf(hA.x, __uint_as_float(((unsigned)W.u[0]) << 16), a0);
    a0 = fmaf(hA.y, __uint_as_float(((unsigned)W.u[1]) << 16), a0);
    a0 = fmaf(hA.z, __uint_as_float(((unsigned)W.u[2]) << 16), a0);
    a0 = fmaf(hA.w, __uint_as_float(((unsigned)W.u[3]) << 16), a0);
    a1 = fmaf(hB.x, __uint_as_float(((unsigned)W.u[4]) << 16), a1);
    a1 = fmaf(hB.y, __uint_as_float(((unsigned)W.u[5]) << 16), a1);
    a1 = fmaf(hB.z, __uint_as_float(((unsigned)W.u[6]) << 16), a1);
    a1 = fmaf(hB.w, __uint_as_float(((unsigned)W.u[7]) << 16), a1);
  }
  float v = fold8(a0 + a1);
  if ((l & 56) == 0)
    out[((size_t)s_store * BATCH + rr) * ODIM + jo] = v + bo;
}

__global__ __launch_bounds__(NTHR, 2) void gru_pipe(
    const float* __restrict__ x,
    const float* __restrict__ Wr0, const float* __restrict__ br0,
    const float* __restrict__ Wz0, const float* __restrict__ bz0,
    const float* __restrict__ Wh0, const float* __restrict__ bh0,
    const float* __restrict__ Wr1, const float* __restrict__ br1,
    const float* __restrict__ Wz1, const float* __restrict__ bz1,
    const float* __restrict__ Wh1, const float* __restrict__ bh1,
    const float* __restrict__ Wout, const float* __restrict__ bout,
    float* __restrict__ out, char* __restrict__ ws)
{
  __shared__ ushortT WSH[53248];     // 104 KB: WA | WB
  __shared__ float red[4][64][4];

  const int blk = blockIdx.x;
  const int tid = threadIdx.x;
  const int l = tid & 63;
  const int w = tid >> 6;
  const int colL = l & 15;

  unsigned* sy = (unsigned*)ws;
  float* h0f  = (float*)(ws + 4096);                 // 256 KB (zeroed)
  float* h1f  = (float*)(ws + 266240);               // 2 x 256 KB (zeroed)
  float* z0f  = (float*)(ws + 790528);
  float* z1f  = (float*)(ws + 1052672);
  ushortT* Mh0  = (ushortT*)(ws + 1314816);          // 2 x 128 KB (zeroed)
  ushortT* Mh1  = (ushortT*)(ws + 1576960);          // 2 x 128 KB (zeroed)
  ushortT* Mrh0 = (ushortT*)(ws + 1839104);          // 128 KB
  ushortT* Mrh1 = (ushortT*)(ws + 1970176);          // 128 KB
  ushortT* Mx   = (ushortT*)(ws + 2101248);          // 2 x 32 KB

  ushortT* WA = WSH;
  ushortT* WB = WSH + (blk < 128 ? 20480 : 32768);

  // ---- one-time weight staging (bf16, fragment order) ----
  if (blk < 128) {
    const int j0 = blk * 8;
    for (int u = tid; u < 40 * 4 * 16; u += NTHR) {
      int kt = u >> 6, g = (u >> 4) & 3, c = u & 15;
      const float* src = (c < 8 ? Wr0 + (size_t)(j0 + c) * 1280
                                : Wz0 + (size_t)(j0 + c - 8) * 1280) + kt * 32 + g * 4;
      pack2(src, &WA[(size_t)u * 8]);
    }
  } else {
    const int j1 = (blk - 128) * 8;
    for (int u = tid; u < 64 * 4 * 16; u += NTHR) {
      int kt = u >> 6, g = (u >> 4) & 3, c = u & 15;
      const float* src = (c < 8 ? Wr1 + (size_t)(j1 + c) * 2048
                                : Wz1 + (size_t)(j1 + c - 8) * 2048) + kt * 32 + g * 4;
      pack2(src, &WA[(size_t)u * 8]);
    }
  }
  if (blk < 64) {
    const int c0 = blk * 16;
    for (int u = tid; u < 40 * 4 * 16; u += NTHR) {
      int kt = u >> 6, g = (u >> 4) & 3, c = u & 15;
      pack2(Wh0 + (size_t)(c0 + c) * 1280 + kt * 32 + g * 4, &WB[(size_t)u * 8]);
    }
  } else if (blk < 128) {
    const int c0 = (blk - 64) * 16;
    for (int u = tid; u < 64 * 4 * 16; u += NTHR) {
      int kt = u >> 6, g = (u >> 4) & 3, c = u & 15;
      pack2(Wh1 + (size_t)(c0 + c) * 2048 + kt * 32 + g * 4, &WB[(size_t)u * 8]);
    }
  } else {
    for (int u = tid; u < 256; u += NTHR) {
      float4 a = *(const float4*)(Wout + (size_t)(blk - 128) * HDIM + (u << 2));
      WB[(u << 2) + 0] = f2bf(a.x);
      WB[(u << 2) + 1] = f2bf(a.y);
      WB[(u << 2) + 2] = f2bf(a.z);
      WB[(u << 2) + 3] = f2bf(a.w);
    }
  }
  // x(0) mirror -> Mx buf 0 (blocks >= 128, 16 units each)
  if (blk >= 128 && tid < 16) {
    int u = ((blk - 128) << 4) + tid;
    int kt = u >> 8, mtu = (u >> 6) & 3, lane = u & 63;
    int row = (mtu << 4) + (lane & 15), gg = lane >> 4;
    pack2(x + (size_t)row * IDIM + (kt << 5) + (gg << 2), Mx + (size_t)u * 8);
  }

  // ---- per-thread constants ----
  float biasA = 0.f, biasB = 0.f, bo = 0.f;
  int cgA = 0, cgB = 0;
  if (blk < 128) {
    cgA = (blk << 3) + (colL & 7);
    biasA = (colL < 8) ? br0[cgA] : bz0[cgA];
  } else {
    cgA = ((blk - 128) << 3) + (colL & 7);
    biasA = (colL < 8) ? br1[cgA] : bz1[cgA];
  }
  if (blk < 64)        { cgB = (blk << 4) + colL;        biasB = bh0[cgB]; }
  else if (blk < 128)  { cgB = ((blk - 64) << 4) + colL; biasB = bh1[cgB]; }
  else                 { bo = bout[blk - 128]; }

  unsigned sidx = 0;
  gsync(sy, blk, ++sidx);

  for (int i = 0; i <= SLEN; ++i) {
    const int pc = i & 1, pp = (i ^ 1) & 1;
    const ushortT* MxP  = Mx  + (size_t)pc * 16384;
    const ushortT* Mh0p = Mh0 + (size_t)pp * 65536;
    const ushortT* Mh1p = Mh1 + (size_t)pp * 65536;
    const float*   h1prev = h1f + (size_t)pp * 65536;
    float*         h1cur  = h1f + (size_t)pc * 65536;
    ushortT* Mh0w = Mh0 + (size_t)pc * 65536;
    ushortT* Mh1w = Mh1 + (size_t)pc * 65536;

    // ================= Phase A: gates =================
    if (blk < 128) {
      if (i < SLEN) {
        f32x4 acc = stage_mm16<40, 8>(MxP, Mh0p, WA, red, l, w);
        if (w < 4) {
          #pragma unroll
          for (int r = 0; r < 4; ++r) {
            int row = (w << 4) + ((l >> 4) << 2) + r;
            float sg = 1.f / (1.f + __expf(-(acc[r] + biasA)));
            if (colL < 8) mir_store(Mrh0, row, cgA, sg * h0f[(size_t)row * HDIM + cgA]);
            else          z0f[(size_t)row * HDIM + cgA] = sg;
          }
        }
      }
    } else {
      if (i >= 1) {
        f32x4 acc = stage_mm16<64, 32>(Mh0p, Mh1p, WA, red, l, w);
        if (w < 4) {
          #pragma unroll
          for (int r = 0; r < 4; ++r) {
            int row = (w << 4) + ((l >> 4) << 2) + r;
            float sg = 1.f / (1.f + __expf(-(acc[r] + biasA)));
            if (colL < 8) mir_store(Mrh1, row, cgA, sg * h1prev[(size_t)row * HDIM + cgA]);
            else          z1f[(size_t)row * HDIM + cgA] = sg;
          }
        }
      }
    }
    gsync(sy, blk, ++sidx);

    // ================= Phase B: candidates + out =================
    if (blk < 64) {
      if (i < SLEN) {
        f32x4 acc = stage_mm16<40, 8>(MxP, Mrh0, WB, red, l, w);
        if (w < 4) {
          #pragma unroll
          for (int r = 0; r < 4; ++r) {
            int row = (w << 4) + ((l >> 4) << 2) + r;
            float ht = tanhf(acc[r] + biasB);
            float zv = z0f[(size_t)row * HDIM + cgB];
            float hp = h0f[(size_t)row * HDIM + cgB];
            float hn = fmaf(zv, ht - hp, hp);
            h0f[(size_t)row * HDIM + cgB] = hn;
            mir_store(Mh0w, row, cgB, hn);
          }
        }
      }
    } else if (blk < 128) {
      if (i >= 1) {
        f32x4 acc = stage_mm16<64, 32>(Mh0p, Mrh1, WB, red, l, w);
        if (w < 4) {
          #pragma unroll
          for (int r = 0; r < 4; ++r) {
            int row = (w << 4) + ((l >> 4) << 2) + r;
            float ht = tanhf(acc[r] + biasB);
            float zv = z1f[(size_t)row * HDIM + cgB];
            float hp = h1prev[(size_t)row * HDIM + cgB];
            float hn = fmaf(zv, ht - hp, hp);
            h1cur[(size_t)row * HDIM + cgB] = hn;
            mir_store(Mh1w, row, cgB, hn);
          }
        }
      }
    } else {
      if (i + 1 < SLEN && tid < 16) {
        ushortT* MxW = Mx + (size_t)((i + 1) & 1) * 16384;
        int u = ((blk - 128) << 4) + tid;
        int kt = u >> 8, mtu = (u >> 6) & 3, lane = u & 63;
        int row = (mtu << 4) + (lane & 15), gg = lane >> 4;
        pack2(x + ((size_t)(i + 1) * BATCH + row) * IDIM + (kt << 5) + (gg << 2),
              MxW + (size_t)u * 8);
      }
      if (i >= 2)
        out_dot(h1prev, WB, bo, out, i - 2, blk - 128, tid);
    }
    gsync(sy, blk, ++sidx);
  }

  // ---- epilogue: out(SLEN-1) from h1f buf0; finals h0f|h1f0 contiguous ----
  if (blk >= 128)
    out_dot(h1f, WB, bo, out, SLEN - 1, blk - 128, tid);
  {
    const size_t base = (size_t)SLEN * BATCH * ODIM;
    const int u = blk * NTHR + tid;          // 0..131071
    out[base + u] = h0f[u];                  // h0f then h1f[0], contiguous
  }
}

extern "C" void kernel_launch(void* const* d_in, const int* in_sizes, int n_in,
                              void* d_out, int out_size, void* d_ws, size_t ws_size,
                              hipStream_t stream) {
  const float* xx  = (const float*)d_in[0];
  const float* Wr0 = (const float*)d_in[1];
  const float* br0 = (const float*)d_in[2];
  const float* Wz0 = (const float*)d_in[3];
  const float* bz0 = (const float*)d_in[4];
  const float* Wh0 = (const float*)d_in[5];
  const float* bh0 = (const float*)d_in[6];
  const float* Wr1 = (const float*)d_in[7];
  const float* br1 = (const float*)d_in[8];
  const float* Wz1 = (const float*)d_in[9];
  const float* bz1 = (const float*)d_in[10];
  const float* Wh1 = (const float*)d_in[11];
  const float* bh1 = (const float*)d_in[12];
  const float* Wou = (const float*)d_in[13];
  const float* bou = (const float*)d_in[14];

  // zero entire state region (sy, flags, h0f, h1f[2], z, mirrors)
  hipMemsetAsync(d_ws, 0, 2166784, stream);

  gru_pipe<<<dim3(NBLK), dim3(NTHR), 0, stream>>>(
      xx, Wr0, br0, Wz0, bz0, Wh0, bh0,
      Wr1, br1, Wz1, bz1, Wh1, bh1, Wou, bou,
      (float*)d_out, (char*)d_ws);
}

// Round 5
// 18554.642 us; speedup vs baseline: 11.5640x; 1.2374x over previous
//
#include <hip/hip_runtime.h>

#define SLEN 512
#define BATCH 64
#define IDIM 256
#define HDIM 1024
#define ODIM 128
#define NBLK 256
#define NTHR 512
#define AGENT __HIP_MEMORY_SCOPE_AGENT

typedef unsigned short ushortT;
typedef __attribute__((ext_vector_type(8))) short short8;
typedef __attribute__((ext_vector_type(4))) float f32x4;

__device__ __forceinline__ ushortT f2bf(float f) {
  unsigned u = __float_as_uint(f);
  unsigned r = (u + 0x7FFFu + ((u >> 16) & 1u)) >> 16;
  return (ushortT)r;
}

// pack A/B fragment halves: src[0..3] -> e0..3, src[16..19] -> e4..7
__device__ __forceinline__ void pack2(const float* __restrict__ s, ushortT* d) {
  float4 a = *(const float4*)s;
  float4 b = *(const float4*)(s + 16);
  short8 v;
  v[0]=(short)f2bf(a.x); v[1]=(short)f2bf(a.y); v[2]=(short)f2bf(a.z); v[3]=(short)f2bf(a.w);
  v[4]=(short)f2bf(b.x); v[5]=(short)f2bf(b.y); v[6]=(short)f2bf(b.z); v[7]=(short)f2bf(b.w);
  *(short8*)d = v;
}

// store one f32 into fragment-ordered bf16 mirror at (row, column cL)
__device__ __forceinline__ void mir_store(ushortT* M, int row, int cL, float v) {
  int kt = cL >> 5, c5 = cL & 31;
  int h = c5 >> 4, g = (c5 >> 2) & 3, j = c5 & 3;
  int u = ((kt * 4 + (row >> 4)) * 64) + 16 * g + (row & 15);
  M[(size_t)u * 8 + h * 4 + j] = f2bf(v);
}

// Parallel-sweep grid barrier: 64 leaves (4 blocks each, cumulative counts);
// block 0 wave 0 polls all 64 leaves in parallel (lane i <-> leaf i), fences,
// fans out to 64 flag lines; each flag polled by 4 blocks (relaxed) + fence.
__device__ __forceinline__ void gsync(unsigned* sy, int blk, int tid, unsigned idx) {
  __syncthreads();
  if (tid == 0) {
    __threadfence();
    __hip_atomic_fetch_add(&sy[16 * (blk >> 2)], 1u, __ATOMIC_RELAXED, AGENT);
  }
  if (blk == 0 && tid < 64) {
    const unsigned tgt = 4u * idx;
    while (__hip_atomic_load(&sy[16 * tid], __ATOMIC_RELAXED, AGENT) < tgt)
      __builtin_amdgcn_s_sleep(1);
    __threadfence();
    __hip_atomic_store(&sy[1024 + 16 * tid], idx, __ATOMIC_RELAXED, AGENT);
  }
  if (tid == 0) {
    unsigned* f = &sy[1024 + 16 * (blk >> 2)];
    while (__hip_atomic_load(f, __ATOMIC_RELAXED, AGENT) < idx)
      __builtin_amdgcn_s_sleep(1);
    __threadfence();
  }
  __syncthreads();
}

__device__ __forceinline__ float fold8(float v) {
  v += __shfl_xor(v, 8);
  v += __shfl_xor(v, 16);
  v += __shfl_xor(v, 32);
  return v;
}

__device__ __forceinline__ short8 lda_(const ushortT* __restrict__ mA,
                                       const ushortT* __restrict__ mB,
                                       int kt, int split, int mt, int l) {
  const ushortT* p = (kt < split)
      ? mA + (size_t)((kt * 4 + mt) * 64 + l) * 8
      : mB + (size_t)(((kt - split) * 4 + mt) * 64 + l) * 8;
  return *(const short8*)p;
}

// N=16 MFMA stage, A = [mA (SPLIT kts) | mB], B = 16 weight cols in WL (LDS).
// 8 waves = 4 M-tiles x 2 K-halves; ALL H loads issued before MFMAs (one drain).
template<int NKT, int SPLIT>
__device__ __forceinline__ f32x4 stage_mm16(
    const ushortT* __restrict__ mA, const ushortT* __restrict__ mB,
    const ushortT* WL, float (*red)[64][4], int l, int w)
{
  const int mt = w & 3, kh = w >> 2;
  constexpr int H = NKT / 2;
  const int lo = kh * H;
  const int g = l >> 4, col = l & 15;
  f32x4 acc = {0.f, 0.f, 0.f, 0.f};
  short8 af[H];
  #pragma unroll
  for (int t = 0; t < H; ++t) af[t] = lda_(mA, mB, lo + t, SPLIT, mt, l);
  #pragma unroll
  for (int t = 0; t < H; ++t) {
    short8 b = *(const short8*)(&WL[(size_t)(((lo + t) * 4 + g) * 16 + col) * 8]);
    acc = __builtin_amdgcn_mfma_f32_16x16x32_bf16(af[t], b, acc, 0, 0, 0);
  }
  if (w >= 4) *(f32x4*)&red[w - 4][l][0] = acc;
  __syncthreads();
  if (w < 4) { f32x4 o = *(f32x4*)&red[w][l][0]; acc += o; }
  return acc;
}

// out = h1 @ Wout^T from the bf16 mirror (fragment order). Lane owns row rr,
// k-slice ks (4 kts); 16 x 16B mirror loads, weights from linear WLo in LDS.
__device__ __forceinline__ void out_dot(const ushortT* __restrict__ Mh1p,
                                        const ushortT* WLo, float bo,
                                        float* __restrict__ out,
                                        int s_store, int jo, int tid) {
  const int l = tid & 63, w = tid >> 6;
  const int rr = (w << 3) + (l & 7);
  const int ks = l >> 3;
  const int mt = rr >> 4, r15 = rr & 15;
  float a0 = 0.f;
  #pragma unroll
  for (int q = 0; q < 4; ++q) {
    const int kt = (ks << 2) + q;
    #pragma unroll
    for (int gg = 0; gg < 4; ++gg) {
      const int u = ((kt << 2) + mt) * 64 + (gg << 4) + r15;
      union { short8 v; ushortT us[8]; } M;
      M.v = *(const short8*)(Mh1p + (size_t)u * 8);
      unsigned long long wlo = *(const unsigned long long*)(WLo + (kt << 5) + (gg << 2));
      unsigned long long whi = *(const unsigned long long*)(WLo + (kt << 5) + 16 + (gg << 2));
      #pragma unroll
      for (int j = 0; j < 4; ++j) {
        float mv = __uint_as_float(((unsigned)M.us[j]) << 16);
        float wv = __uint_as_float((unsigned)((wlo >> (16 * j)) & 0xFFFFu) << 16);
        a0 = fmaf(mv, wv, a0);
      }
      #pragma unroll
      for (int j = 0; j < 4; ++j) {
        float mv = __uint_as_float(((unsigned)M.us[4 + j]) << 16);
        float wv = __uint_as_float((unsigned)((whi >> (16 * j)) & 0xFFFFu) << 16);
        a0 = fmaf(mv, wv, a0);
      }
    }
  }
  float v = fold8(a0);
  if ((l & 56) == 0)
    out[((size_t)s_store * BATCH + rr) * ODIM + jo] = v + bo;
}

__global__ __launch_bounds__(NTHR, 2) void gru_pipe(
    const float* __restrict__ x,
    const float* __restrict__ Wr0, const float* __restrict__ br0,
    const float* __restrict__ Wz0, const float* __restrict__ bz0,
    const float* __restrict__ Wh0, const float* __restrict__ bh0,
    const float* __restrict__ Wr1, const float* __restrict__ br1,
    const float* __restrict__ Wz1, const float* __restrict__ bz1,
    const float* __restrict__ Wh1, const float* __restrict__ bh1,
    const float* __restrict__ Wout, const float* __restrict__ bout,
    float* __restrict__ out, char* __restrict__ ws)
{
  __shared__ ushortT WSH[53248];     // 104 KB: WA | WB
  __shared__ float red[4][64][4];

  const int blk = blockIdx.x;
  const int tid = threadIdx.x;
  const int l = tid & 63;
  const int w = tid >> 6;
  const int colL = l & 15;

  unsigned* sy = (unsigned*)ws;                      // 8 KB: 64 leaves + 64 flags
  float* h0f  = (float*)(ws + 8192);                 // 256 KB (zeroed)
  float* h1f  = (float*)(ws + 270336);               // 2 x 256 KB (zeroed)
  float* z0f  = (float*)(ws + 794624);
  float* z1f  = (float*)(ws + 1056768);
  ushortT* Mh0  = (ushortT*)(ws + 1318912);          // 2 x 128 KB (zeroed)
  ushortT* Mh1  = (ushortT*)(ws + 1581056);          // 2 x 128 KB (zeroed)
  ushortT* Mrh0 = (ushortT*)(ws + 1843200);          // 128 KB
  ushortT* Mrh1 = (ushortT*)(ws + 1974272);          // 128 KB
  ushortT* Mx   = (ushortT*)(ws + 2105344);          // 2 x 32 KB

  ushortT* WA = WSH;
  ushortT* WB = WSH + (blk < 128 ? 20480 : 32768);

  // ---- one-time weight staging (bf16, fragment order) ----
  if (blk < 128) {
    const int j0 = blk * 8;
    for (int u = tid; u < 40 * 4 * 16; u += NTHR) {
      int kt = u >> 6, g = (u >> 4) & 3, c = u & 15;
      const float* src = (c < 8 ? Wr0 + (size_t)(j0 + c) * 1280
                                : Wz0 + (size_t)(j0 + c - 8) * 1280) + kt * 32 + g * 4;
      pack2(src, &WA[(size_t)u * 8]);
    }
  } else {
    const int j1 = (blk - 128) * 8;
    for (int u = tid; u < 64 * 4 * 16; u += NTHR) {
      int kt = u >> 6, g = (u >> 4) & 3, c = u & 15;
      const float* src = (c < 8 ? Wr1 + (size_t)(j1 + c) * 2048
                                : Wz1 + (size_t)(j1 + c - 8) * 2048) + kt * 32 + g * 4;
      pack2(src, &WA[(size_t)u * 8]);
    }
  }
  if (blk < 64) {
    const int c0 = blk * 16;
    for (int u = tid; u < 40 * 4 * 16; u += NTHR) {
      int kt = u >> 6, g = (u >> 4) & 3, c = u & 15;
      pack2(Wh0 + (size_t)(c0 + c) * 1280 + kt * 32 + g * 4, &WB[(size_t)u * 8]);
    }
  } else if (blk < 128) {
    const int c0 = (blk - 64) * 16;
    for (int u = tid; u < 64 * 4 * 16; u += NTHR) {
      int kt = u >> 6, g = (u >> 4) & 3, c = u & 15;
      pack2(Wh1 + (size_t)(c0 + c) * 2048 + kt * 32 + g * 4, &WB[(size_t)u * 8]);
    }
  } else {
    for (int u = tid; u < 256; u += NTHR) {
      float4 a = *(const float4*)(Wout + (size_t)(blk - 128) * HDIM + (u << 2));
      WB[(u << 2) + 0] = f2bf(a.x);
      WB[(u << 2) + 1] = f2bf(a.y);
      WB[(u << 2) + 2] = f2bf(a.z);
      WB[(u << 2) + 3] = f2bf(a.w);
    }
  }
  // x(0) mirror -> Mx buf 0 (blocks >= 128, 16 units each)
  if (blk >= 128 && tid < 16) {
    int u = ((blk - 128) << 4) + tid;
    int kt = u >> 8, mtu = (u >> 6) & 3, lane = u & 63;
    int row = (mtu << 4) + (lane & 15), gg = lane >> 4;
    pack2(x + (size_t)row * IDIM + (kt << 5) + (gg << 2), Mx + (size_t)u * 8);
  }

  // ---- per-thread constants ----
  float biasA = 0.f, biasB = 0.f, bo = 0.f;
  int cgA = 0, cgB = 0;
  if (blk < 128) {
    cgA = (blk << 3) + (colL & 7);
    biasA = (colL < 8) ? br0[cgA] : bz0[cgA];
  } else {
    cgA = ((blk - 128) << 3) + (colL & 7);
    biasA = (colL < 8) ? br1[cgA] : bz1[cgA];
  }
  if (blk < 64)        { cgB = (blk << 4) + colL;        biasB = bh0[cgB]; }
  else if (blk < 128)  { cgB = ((blk - 64) << 4) + colL; biasB = bh1[cgB]; }
  else                 { bo = bout[blk - 128]; }

  unsigned sidx = 0;
  gsync(sy, blk, tid, ++sidx);

  for (int i = 0; i <= SLEN; ++i) {
    const int pc = i & 1, pp = (i ^ 1) & 1;
    const ushortT* MxP  = Mx  + (size_t)pc * 16384;
    const ushortT* Mh0p = Mh0 + (size_t)pp * 65536;
    const ushortT* Mh1p = Mh1 + (size_t)pp * 65536;
    const float*   h1prev = h1f + (size_t)pp * 65536;
    float*         h1cur  = h1f + (size_t)pc * 65536;
    ushortT* Mh0w = Mh0 + (size_t)pc * 65536;
    ushortT* Mh1w = Mh1 + (size_t)pc * 65536;

    // ================= Phase A: gates =================
    if (blk < 128) {
      if (i < SLEN) {
        f32x4 acc = stage_mm16<40, 8>(MxP, Mh0p, WA, red, l, w);
        if (w < 4) {
          #pragma unroll
          for (int r = 0; r < 4; ++r) {
            int row = (w << 4) + ((l >> 4) << 2) + r;
            float sg = 1.f / (1.f + __expf(-(acc[r] + biasA)));
            if (colL < 8) mir_store(Mrh0, row, cgA, sg * h0f[(size_t)row * HDIM + cgA]);
            else          z0f[(size_t)row * HDIM + cgA] = sg;
          }
        }
      }
    } else {
      if (i >= 1) {
        f32x4 acc = stage_mm16<64, 32>(Mh0p, Mh1p, WA, red, l, w);
        if (w < 4) {
          #pragma unroll
          for (int r = 0; r < 4; ++r) {
            int row = (w << 4) + ((l >> 4) << 2) + r;
            float sg = 1.f / (1.f + __expf(-(acc[r] + biasA)));
            if (colL < 8) mir_store(Mrh1, row, cgA, sg * h1prev[(size_t)row * HDIM + cgA]);
            else          z1f[(size_t)row * HDIM + cgA] = sg;
          }
        }
      }
    }
    gsync(sy, blk, tid, ++sidx);

    // ================= Phase B: candidates + out =================
    if (blk < 64) {
      if (i < SLEN) {
        f32x4 acc = stage_mm16<40, 8>(MxP, Mrh0, WB, red, l, w);
        if (w < 4) {
          #pragma unroll
          for (int r = 0; r < 4; ++r) {
            int row = (w << 4) + ((l >> 4) << 2) + r;
            float ht = tanhf(acc[r] + biasB);
            float zv = z0f[(size_t)row * HDIM + cgB];
            float hp = h0f[(size_t)row * HDIM + cgB];
            float hn = fmaf(zv, ht - hp, hp);
            h0f[(size_t)row * HDIM + cgB] = hn;
            mir_store(Mh0w, row, cgB, hn);
          }
        }
      }
    } else if (blk < 128) {
      if (i >= 1) {
        f32x4 acc = stage_mm16<64, 32>(Mh0p, Mrh1, WB, red, l, w);
        if (w < 4) {
          #pragma unroll
          for (int r = 0; r < 4; ++r) {
            int row = (w << 4) + ((l >> 4) << 2) + r;
            float ht = tanhf(acc[r] + biasB);
            float zv = z1f[(size_t)row * HDIM + cgB];
            float hp = h1prev[(size_t)row * HDIM + cgB];
            float hn = fmaf(zv, ht - hp, hp);
            h1cur[(size_t)row * HDIM + cgB] = hn;
            mir_store(Mh1w, row, cgB, hn);
          }
        }
      }
    } else {
      if (i + 1 < SLEN && tid < 16) {
        ushortT* MxW = Mx + (size_t)((i + 1) & 1) * 16384;
        int u = ((blk - 128) << 4) + tid;
        int kt = u >> 8, mtu = (u >> 6) & 3, lane = u & 63;
        int row = (mtu << 4) + (lane & 15), gg = lane >> 4;
        pack2(x + ((size_t)(i + 1) * BATCH + row) * IDIM + (kt << 5) + (gg << 2),
              MxW + (size_t)u * 8);
      }
      if (i >= 2)
        out_dot(Mh1p, WB, bo, out, i - 2, blk - 128, tid);
    }
    gsync(sy, blk, tid, ++sidx);
  }

  // ---- epilogue: out(SLEN-1) from Mh1 parity 0; finals h0f|h1f0 contiguous ----
  if (blk >= 128)
    out_dot(Mh1, WB, bo, out, SLEN - 1, blk - 128, tid);
  {
    const size_t base = (size_t)SLEN * BATCH * ODIM;
    const int u = blk * NTHR + tid;          // 0..131071
    out[base + u] = h0f[u];                  // h0f then h1f[0], contiguous
  }
}

extern "C" void kernel_launch(void* const* d_in, const int* in_sizes, int n_in,
                              void* d_out, int out_size, void* d_ws, size_t ws_size,
                              hipStream_t stream) {
  const float* xx  = (const float*)d_in[0];
  const float* Wr0 = (const float*)d_in[1];
  const float* br0 = (const float*)d_in[2];
  const float* Wz0 = (const float*)d_in[3];
  const float* bz0 = (const float*)d_in[4];
  const float* Wh0 = (const float*)d_in[5];
  const float* bh0 = (const float*)d_in[6];
  const float* Wr1 = (const float*)d_in[7];
  const float* br1 = (const float*)d_in[8];
  const float* Wz1 = (const float*)d_in[9];
  const float* bz1 = (const float*)d_in[10];
  const float* Wh1 = (const float*)d_in[11];
  const float* bh1 = (const float*)d_in[12];
  const float* Wou = (const float*)d_in[13];
  const float* bou = (const float*)d_in[14];

  // zero entire state region (sy, h0f, h1f[2], z, mirrors)
  hipMemsetAsync(d_ws, 0, 2170880, stream);

  gru_pipe<<<dim3(NBLK), dim3(NTHR), 0, stream>>>(
      xx, Wr0, br0, Wz0, bz0, Wh0, bh0,
      Wr1, br1, Wz1, bz1, Wh1, bh1, Wou, bou,
      (float*)d_out, (char*)d_ws);
}